// Round 8
// baseline (352.660 us; speedup 1.0000x reference)
//
#include <hip/hip_runtime.h>
#include <hip/hip_bf16.h>

#define F_NODE 128
#define BINCAP 64

typedef float f32x4 __attribute__((ext_vector_type(4)));
typedef float f32x2 __attribute__((ext_vector_type(2)));

__device__ __forceinline__ float bflo(unsigned int v) {
    return __uint_as_float(v << 16);
}
__device__ __forceinline__ float bfhi(unsigned int v) {
    return __uint_as_float(v & 0xffff0000u);
}
__device__ __forceinline__ unsigned short bfpack(float f) {
    __hip_bfloat16 b = __float2bfloat16(f);
    return *reinterpret_cast<unsigned short*>(&b);
}

// ---------------------------------------------------------------------------
// K0: fold weights on device.
//  Wnt[f][k] = W_node[k][f]                     (32 x 128 transposed)
//  M2[k][g]  = sum_j Wg_sel[k][j]*Wl_top[j][g&31]  (32 x 64; g<32 -> z)
//  cvec[g]   = sum_j bg[j]*Wl_top[j][g&31] + bl[g&31]
//  Wet[f][k] = W_edge[k][f]                     (32 x 32 transposed)
__global__ void k_prep(const float* __restrict__ Wn,
                       const float* __restrict__ Wgz, const float* __restrict__ Wgh,
                       const float* __restrict__ Wlz, const float* __restrict__ Wlh,
                       const float* __restrict__ bgz, const float* __restrict__ bgh,
                       const float* __restrict__ blz, const float* __restrict__ blh,
                       const float* __restrict__ We,
                       float* __restrict__ Wnt, float* __restrict__ M2,
                       float* __restrict__ cvec, float* __restrict__ Wet) {
    int tid = threadIdx.x;
    for (int j = tid; j < 32 * 128; j += 256) {
        int f = j >> 7, k = j & 127;
        Wnt[j] = Wn[k * 32 + f];
    }
    for (int j = tid; j < 32 * 64; j += 256) {
        int k = j >> 6, g = j & 63, f = g & 31;
        const float* G = (g < 32) ? Wgz : Wgh;
        const float* L = (g < 32) ? Wlz : Wlh;   // top-half rows 0..31 of [64,32]
        float s = 0.f;
        for (int q = 0; q < 32; ++q) s += G[k * 32 + q] * L[q * 32 + f];
        M2[j] = s;
    }
    for (int j = tid; j < 64; j += 256) {
        int f = j & 31;
        const float* L  = (j < 32) ? Wlz : Wlh;
        const float* bg = (j < 32) ? bgz : bgh;
        const float* bl = (j < 32) ? blz : blh;
        float s = bl[f];
        for (int q = 0; q < 32; ++q) s += bg[q] * L[q * 32 + f];
        cvec[j] = s;
    }
    for (int j = tid; j < 32 * 32; j += 256) {
        int f = j >> 5, k = j & 31;
        Wet[j] = We[k * 32 + f];
    }
}

// ---------------------------------------------------------------------------
// FAT kernel, period-16 role interleave (preserves blockIdx%8 == XCD):
//   slot = bid & 15.  slot < 8  -> bin-fill, partition myp = bid&7 (== XCD):
//       scans group-chunk of ALL edges, keeps cols in its 1/8 range ->
//       bin/cursor hot lines stay in this XCD's L2 (write combining).
//   slot >= 8 -> edge matmul out[e] = relu(ea@We+be).w3 + b0 (NT ea loads).
__global__ __launch_bounds__(256) void k_fat(
        const int* __restrict__ row, const int* __restrict__ col,
        int* __restrict__ cursor, int* __restrict__ bin,
        const float* __restrict__ ea, const float* __restrict__ Wet,
        const float* __restrict__ be, const float* __restrict__ Wout,
        const float* __restrict__ bout, float* __restrict__ out,
        int E, unsigned pmul) {
    __shared__ float sW[1024];
    __shared__ float sb[32], sw3[32];
    int bid = blockIdx.x, tid = threadIdx.x;
    int slot = bid & 15;
    int fg   = bid >> 4;
    int G    = gridDim.x >> 4;

    if (slot < 8) {
        // ---- bin fill, partition myp ----
        int myp = bid & 7;
        int CS = (E + G - 1) / G;
        int base = fg * CS;
        int end = base + CS; if (end > E) end = E;
        for (int e = base + tid; e < end; e += 256) {
            int c = __builtin_nontemporal_load(col + e);
            int r = __builtin_nontemporal_load(row + e);
            int p8 = (int)(((unsigned long long)(unsigned)c * pmul) >> 32);
            if (p8 == myp) {
                int p = atomicAdd(&cursor[c], 1);
                if (p < BINCAP) bin[((size_t)c << 6) + p] = r;
            }
        }
        return;
    }

    // ---- edge matmul ----
    for (int j = tid; j < 1024; j += 256) sW[j] = Wet[j];
    if (tid < 32) { sb[tid] = be[tid]; sw3[tid] = Wout[64 + tid]; }
    __syncthreads();
    int chunk = fg * 8 + (slot - 8);
    int e = chunk * 256 + tid;
    if (e >= E) return;
    f32x4 er[8];
    const f32x4* erow = (const f32x4*)(ea + (size_t)e * 32);
    #pragma unroll
    for (int r = 0; r < 8; ++r) er[r] = __builtin_nontemporal_load(erow + r);
    float p = 0.f;
    #pragma unroll 4
    for (int f = 0; f < 32; ++f) {
        const f32x4* wf = (const f32x4*)(sW + f * 32);
        f32x4 v0 = er[0] * wf[0];
        f32x4 v1 = er[1] * wf[1];
        #pragma unroll
        for (int k = 2; k < 8; k += 2) {
            v0 += er[k] * wf[k];
            v1 += er[k + 1] * wf[k + 1];
        }
        f32x4 v = v0 + v1;
        float sfin = (v[0] + v[1]) + (v[2] + v[3]);
        p += fmaxf(sb[f] + sfin, 0.f) * sw3[f];
    }
    __builtin_nontemporal_store(p + bout[0], out + e);
}

// ---------------------------------------------------------------------------
// K2: node encoder, wave-per-node. Lane (f=l&31, kh=l>>5): weight column f,
// K-half kh in 16 f32x4 registers; x staged wave-private in LDS; NT x loads.
//   ysb[i][f] = bf16( relu(x_i @ Wn + bn)[f] )     (unscaled)
__global__ __launch_bounds__(256) void k_enc(
        const float* __restrict__ x, const float* __restrict__ bn,
        const float* __restrict__ Wnt, __hip_bfloat16* __restrict__ ysb, int N) {
    __shared__ float sx[4][128];
    int tid = threadIdx.x;
    int w = tid >> 6, l = tid & 63;
    int f = l & 31, kh = l >> 5;

    f32x4 wreg[16];
    const f32x4* wp = (const f32x4*)(Wnt + f * 128 + kh * 64);
    #pragma unroll
    for (int r = 0; r < 16; ++r) wreg[r] = wp[r];
    float bnf = bn[f];

    int stride = gridDim.x * 4;
    int i = blockIdx.x * 4 + w;
    f32x2 xv = {0.f, 0.f};
    if (i < N)
        xv = __builtin_nontemporal_load((const f32x2*)(x + (size_t)i * F_NODE) + l);

    for (; i < N; i += stride) {
        sx[w][2 * l]     = xv[0];
        sx[w][2 * l + 1] = xv[1];
        int inext = i + stride;
        if (inext < N)
            xv = __builtin_nontemporal_load(
                     (const f32x2*)(x + (size_t)inext * F_NODE) + l);

        const f32x4* sxp = (const f32x4*)(&sx[w][kh * 64]);
        f32x4 a0 = sxp[0] * wreg[0];
        f32x4 a1 = sxp[1] * wreg[1];
        f32x4 a2 = sxp[2] * wreg[2];
        f32x4 a3 = sxp[3] * wreg[3];
        #pragma unroll
        for (int r = 4; r < 16; r += 4) {
            a0 += sxp[r]     * wreg[r];
            a1 += sxp[r + 1] * wreg[r + 1];
            a2 += sxp[r + 2] * wreg[r + 2];
            a3 += sxp[r + 3] * wreg[r + 3];
        }
        f32x4 av = (a0 + a1) + (a2 + a3);
        float acc = (av[0] + av[1]) + (av[2] + av[3]);
        acc += __shfl_xor(acc, 32);
        acc = fmaxf(acc + bnf, 0.f);
        if (l < 32)
            ysb[(size_t)i * 32 + f] = __float2bfloat16(acc);
    }
}

// ---------------------------------------------------------------------------
// K3: in-place scale  ysb[i][:] *= rsqrt(deg_i + 1)  (row = 32 bf16 = 4 uint4)
__global__ __launch_bounds__(256) void k_scale(
        uint4* __restrict__ ysb4, const int* __restrict__ cursor, int N) {
    int t = blockIdx.x * 256 + threadIdx.x;
    if (t >= N * 4) return;
    float d = rsqrtf((float)cursor[t >> 2] + 1.0f);
    uint4 v = ysb4[t];
    unsigned in[4] = {v.x, v.y, v.z, v.w};
    unsigned r[4];
    #pragma unroll
    for (int j = 0; j < 4; ++j) {
        unsigned short ul = bfpack(bflo(in[j]) * d);
        unsigned short uh = bfpack(bfhi(in[j]) * d);
        r[j] = (unsigned)ul | ((unsigned)uh << 16);
    }
    ysb4[t] = make_uint4(r[0], r[1], r[2], r[3]);
}

// ---------------------------------------------------------------------------
// K4: persistent wave-per-node gather. M2 column l held in 32 REGISTERS
// (no per-block LDS staging — r7's 200MB mistake). Lane (q=l&7, s=l>>3):
// uint2 = 4 bf16/lane, 8 lanes/edge -> 8 edges in flight. Epilogue matvec
// via static-index unrolled shfl; Z/Ht split; hr/hc scalars.
__global__ __launch_bounds__(256) void k_gather(
        const int* __restrict__ cursor, const int* __restrict__ bin,
        const unsigned short* __restrict__ ysb,
        const float* __restrict__ M2, const float* __restrict__ cvec,
        const float* __restrict__ Wout,
        float* __restrict__ hr, float* __restrict__ hc, int N) {
    int tid = threadIdx.x;
    int w = tid >> 6, l = tid & 63;
    int q = l & 7, s = l >> 3;

    float mcol[32];
    #pragma unroll
    for (int k = 0; k < 32; ++k) mcol[k] = M2[k * 64 + l];
    float cvl = cvec[l];
    float w0l = Wout[l & 31];
    float w1l = Wout[32 + (l & 31)];

    int stride = gridDim.x * 4;
    for (int c = blockIdx.x * 4 + w; c < N; c += stride) {
        int truec = cursor[c];
        float dc = rsqrtf((float)truec + 1.0f);
        int cnt = truec < BINCAP ? truec : BINCAP;
        const int* bp = bin + ((size_t)c << 6);
        int myr = (l < cnt) ? bp[l] : 0;

        float a0 = 0.f, a1 = 0.f, a2 = 0.f, a3 = 0.f;
        uint2 sv = *(const uint2*)(ysb + (size_t)c * 32 + 4 * q);
        if (s == 0) {
            a0 = bflo(sv.x); a1 = bfhi(sv.x);
            a2 = bflo(sv.y); a3 = bfhi(sv.y);
        }
        for (int j = 0; j < cnt; j += 8) {
            int jj = j + s;
            if (jj < cnt) {
                int r = __shfl(myr, jj);
                uint2 v = *(const uint2*)(ysb + (size_t)r * 32 + 4 * q);
                a0 += bflo(v.x); a1 += bfhi(v.x);
                a2 += bflo(v.y); a3 += bfhi(v.y);
            }
        }
        a0 += __shfl_xor(a0, 8);  a1 += __shfl_xor(a1, 8);
        a2 += __shfl_xor(a2, 8);  a3 += __shfl_xor(a3, 8);
        a0 += __shfl_xor(a0, 16); a1 += __shfl_xor(a1, 16);
        a2 += __shfl_xor(a2, 16); a3 += __shfl_xor(a3, 16);
        a0 += __shfl_xor(a0, 32); a1 += __shfl_xor(a1, 32);
        a2 += __shfl_xor(a2, 32); a3 += __shfl_xor(a3, 32);
        // lane with q=kq now holds S[4kq..4kq+3] in a0..a3

        float acc = 0.f;
        #pragma unroll
        for (int kq = 0; kq < 8; ++kq) {
            float s0 = __shfl(a0, kq), s1 = __shfl(a1, kq);
            float s2 = __shfl(a2, kq), s3 = __shfl(a3, kq);
            acc += s0 * mcol[4 * kq]     + s1 * mcol[4 * kq + 1]
                 + s2 * mcol[4 * kq + 2] + s3 * mcol[4 * kq + 3];
        }
        float a = dc * acc + cvl;
        float v = (l < 32) ? (1.f / (1.f + __expf(-a))) : tanhf(a);
        float o = __shfl_xor(v, 32);
        float h = (1.f - v) * o;             // valid on lanes l<32
        float pr = h * w0l;
        float pc = h * w1l;
        #pragma unroll
        for (int m = 16; m >= 1; m >>= 1) {
            pr += __shfl_xor(pr, m);
            pc += __shfl_xor(pc, m);
        }
        if (l == 0) { hr[c] = pr; hc[c] = pc; }
    }
}

// ---------------------------------------------------------------------------
// K5: out[e] += hr[row[e]] + hc[col[e]]   (hr/hc 400KB each: L2/L3-resident)
__global__ __launch_bounds__(256) void k_edge_add(
        const int* __restrict__ row, const int* __restrict__ col,
        const float* __restrict__ hr, const float* __restrict__ hc,
        float* __restrict__ out, int E) {
    int e = blockIdx.x * 256 + threadIdx.x;
    if (e < E) out[e] += hr[row[e]] + hc[col[e]];
}

// ---------------------------------------------------------------------------
extern "C" void kernel_launch(void* const* d_in, const int* in_sizes, int n_in,
                              void* d_out, int out_size, void* d_ws, size_t ws_size,
                              hipStream_t stream) {
    const float* x    = (const float*)d_in[0];
    const int*   ei   = (const int*)  d_in[1];
    const float* ea   = (const float*)d_in[2];
    const float* Wn   = (const float*)d_in[3];
    const float* bn   = (const float*)d_in[4];
    const float* We   = (const float*)d_in[5];
    const float* be   = (const float*)d_in[6];
    const float* Wgz  = (const float*)d_in[7];
    const float* bgz  = (const float*)d_in[8];
    // d_in[9..10] = Wg_r, bg_r : dead (h0 == 0)
    const float* Wgh  = (const float*)d_in[11];
    const float* bgh  = (const float*)d_in[12];
    const float* Wlz  = (const float*)d_in[13];
    const float* blz  = (const float*)d_in[14];
    // d_in[15..16] = Wl_r, bl_r : dead
    const float* Wlh  = (const float*)d_in[17];
    const float* blh  = (const float*)d_in[18];
    const float* Wout = (const float*)d_in[19];
    const float* bout = (const float*)d_in[20];

    int N = in_sizes[0] / F_NODE;
    int E = in_sizes[1] / 2;
    const int* row = ei;
    const int* col = ei + E;

    // partition magic: p = (c * pmul) >> 32  in [0,8)
    unsigned pmul = (unsigned)(((8ULL << 32) + (unsigned long long)N - 1)
                               / (unsigned long long)N);

    // ws layout (float units):
    // ysb(bf16)[32N]=16N | bin(int)[64N] | Wnt[4096] | M2[2048] | Wet[1024]
    // | cvec[64] | hr[N] | hc[N] | cursor(int)[N]
    float* ws    = (float*)d_ws;
    __hip_bfloat16* ysb = (__hip_bfloat16*)ws;
    int*   bin   = (int*)(ws + (size_t)16 * N);
    float* Wnt   = ws + (size_t)80 * N;
    float* M2    = Wnt + 4096;
    float* Wet   = M2 + 2048;
    float* cvec  = Wet + 1024;
    float* hr    = cvec + 64;
    float* hc    = hr + N;
    int*   cursor= (int*)(hc + N);
    float* out   = (float*)d_out;

    hipMemsetAsync(cursor, 0, (size_t)N * sizeof(int), stream);

    k_prep<<<1, 256, 0, stream>>>(Wn, Wgz, Wgh, Wlz, Wlh, bgz, bgh, blz, blh, We,
                                  Wnt, M2, cvec, Wet);
    int nMM = (E + 255) / 256;
    int G   = (nMM + 7) / 8;
    k_fat<<<G * 16, 256, 0, stream>>>(row, col, cursor, bin, ea, Wet, be, Wout,
                                      bout, out, E, pmul);
    k_enc<<<768, 256, 0, stream>>>(x, bn, Wnt, ysb, N);
    k_scale<<<(4 * N + 255) / 256, 256, 0, stream>>>((uint4*)ysb, cursor, N);
    k_gather<<<2048, 256, 0, stream>>>(cursor, bin, (const unsigned short*)ysb,
                                       M2, cvec, Wout, hr, hc, N);
    k_edge_add<<<nMM, 256, 0, stream>>>(row, col, hr, hc, out, E);
}

// Round 9
// 334.391 us; speedup vs baseline: 1.0546x; 1.0546x over previous
//
#include <hip/hip_runtime.h>
#include <hip/hip_bf16.h>

#define F_NODE 128
#define BINCAP 64

typedef float f32x4 __attribute__((ext_vector_type(4)));
typedef float f32x2 __attribute__((ext_vector_type(2)));

__device__ __forceinline__ float bflo(unsigned int v) {
    return __uint_as_float(v << 16);
}
__device__ __forceinline__ float bfhi(unsigned int v) {
    return __uint_as_float(v & 0xffff0000u);
}

// ---------------------------------------------------------------------------
// K0: fold weights on device.
//  Wnt[f][k] = W_node[k][f]                     (32 x 128 transposed)
//  M2[k][g]  = sum_j Wg_sel[k][j]*Wl_top[j][g&31]  (32 x 64; g<32 -> z)
//  cvec[g]   = sum_j bg[j]*Wl_top[j][g&31] + bl[g&31]
//  Wet[f][k] = W_edge[k][f]                     (32 x 32 transposed)
__global__ void k_prep(const float* __restrict__ Wn,
                       const float* __restrict__ Wgz, const float* __restrict__ Wgh,
                       const float* __restrict__ Wlz, const float* __restrict__ Wlh,
                       const float* __restrict__ bgz, const float* __restrict__ bgh,
                       const float* __restrict__ blz, const float* __restrict__ blh,
                       const float* __restrict__ We,
                       float* __restrict__ Wnt, float* __restrict__ M2,
                       float* __restrict__ cvec, float* __restrict__ Wet) {
    int tid = threadIdx.x;
    for (int j = tid; j < 32 * 128; j += 256) {
        int f = j >> 7, k = j & 127;
        Wnt[j] = Wn[k * 32 + f];
    }
    for (int j = tid; j < 32 * 64; j += 256) {
        int k = j >> 6, g = j & 63, f = g & 31;
        const float* G = (g < 32) ? Wgz : Wgh;
        const float* L = (g < 32) ? Wlz : Wlh;   // top-half rows 0..31 of [64,32]
        float s = 0.f;
        for (int q = 0; q < 32; ++q) s += G[k * 32 + q] * L[q * 32 + f];
        M2[j] = s;
    }
    for (int j = tid; j < 64; j += 256) {
        int f = j & 31;
        const float* L  = (j < 32) ? Wlz : Wlh;
        const float* bg = (j < 32) ? bgz : bgh;
        const float* bl = (j < 32) ? blz : blh;
        float s = bl[f];
        for (int q = 0; q < 32; ++q) s += bg[q] * L[q * 32 + f];
        cvec[j] = s;
    }
    for (int j = tid; j < 32 * 32; j += 256) {
        int f = j >> 5, k = j & 31;
        Wet[j] = We[k * 32 + f];
    }
}

// ---------------------------------------------------------------------------
// FAT kernel, launched TWICE (sequential col-half passes).
//  slot = bid%3: 0,1 -> bin-fill scan chunks (keep only cols in [clo,chi):
//      instantaneous hot-line set = 3.2MB -> survives in L2, writes combine),
//  slot 2 -> edge matmul on this launch's edge half (NT ea loads).
// edge_index uses NORMAL loads: 12.8MB, L3-resident across passes.
__global__ __launch_bounds__(256) void k_fat(
        const int* __restrict__ row, const int* __restrict__ col,
        int* __restrict__ cursor, int* __restrict__ bin,
        const float* __restrict__ ea, const float* __restrict__ Wet,
        const float* __restrict__ be, const float* __restrict__ Wout,
        const float* __restrict__ bout, float* __restrict__ out,
        int E, int clo, int chi, int e0MM) {
    __shared__ float sW[1024];
    __shared__ float sb[32], sw3[32];
    int bid = blockIdx.x, tid = threadIdx.x;
    int slot = bid % 3;
    int sub  = bid / 3;

    if (slot < 2) {
        // ---- bin fill: scan chunk of the FULL edge list, filter col range ----
        int e = (sub * 2 + slot) * 256 + tid;
        if (e < E) {
            int c = col[e];
            if (c >= clo && c < chi) {
                int r = row[e];
                int p = atomicAdd(&cursor[c], 1);
                if (p < BINCAP) bin[((size_t)c << 6) + p] = r;
            }
        }
        return;
    }

    // ---- edge matmul: out[e] = relu(ea@We+be).w3 + b0 ----
    for (int j = tid; j < 1024; j += 256) sW[j] = Wet[j];
    if (tid < 32) { sb[tid] = be[tid]; sw3[tid] = Wout[64 + tid]; }
    __syncthreads();
    int e = e0MM + sub * 256 + tid;
    if (e >= E) return;
    f32x4 er[8];
    const f32x4* erow = (const f32x4*)(ea + (size_t)e * 32);
    #pragma unroll
    for (int r = 0; r < 8; ++r) er[r] = __builtin_nontemporal_load(erow + r);
    float p = 0.f;
    #pragma unroll 4
    for (int f = 0; f < 32; ++f) {
        const f32x4* wf = (const f32x4*)(sW + f * 32);
        f32x4 v0 = er[0] * wf[0];
        f32x4 v1 = er[1] * wf[1];
        #pragma unroll
        for (int k = 2; k < 8; k += 2) {
            v0 += er[k] * wf[k];
            v1 += er[k + 1] * wf[k + 1];
        }
        f32x4 v = v0 + v1;
        float sfin = (v[0] + v[1]) + (v[2] + v[3]);
        p += fmaxf(sb[f] + sfin, 0.f) * sw3[f];
    }
    __builtin_nontemporal_store(p + bout[0], out + e);
}

// ---------------------------------------------------------------------------
// K2: node encoder (runs AFTER fill -> degrees known). Wave-per-node:
// lane (f=l&31, kh=l>>5), weight column f K-half kh in 16 f32x4 registers;
// x staged wave-private in LDS; NT x loads.  Stores PRE-SCALED:
//   ysb[i][f] = bf16( rsqrt(deg_i+1) * relu(x_i @ Wn + bn)[f] )
__global__ __launch_bounds__(256) void k_enc(
        const float* __restrict__ x, const float* __restrict__ bn,
        const float* __restrict__ Wnt, const int* __restrict__ cursor,
        __hip_bfloat16* __restrict__ ysb, int N) {
    __shared__ float sx[4][128];
    int tid = threadIdx.x;
    int w = tid >> 6, l = tid & 63;
    int f = l & 31, kh = l >> 5;

    f32x4 wreg[16];
    const f32x4* wp = (const f32x4*)(Wnt + f * 128 + kh * 64);
    #pragma unroll
    for (int r = 0; r < 16; ++r) wreg[r] = wp[r];
    float bnf = bn[f];

    int stride = gridDim.x * 4;
    int i = blockIdx.x * 4 + w;
    f32x2 xv = {0.f, 0.f};
    if (i < N)
        xv = __builtin_nontemporal_load((const f32x2*)(x + (size_t)i * F_NODE) + l);

    for (; i < N; i += stride) {
        sx[w][2 * l]     = xv[0];
        sx[w][2 * l + 1] = xv[1];
        int inext = i + stride;
        if (inext < N)
            xv = __builtin_nontemporal_load(
                     (const f32x2*)(x + (size_t)inext * F_NODE) + l);

        const f32x4* sxp = (const f32x4*)(&sx[w][kh * 64]);
        f32x4 a0 = sxp[0] * wreg[0];
        f32x4 a1 = sxp[1] * wreg[1];
        f32x4 a2 = sxp[2] * wreg[2];
        f32x4 a3 = sxp[3] * wreg[3];
        #pragma unroll
        for (int r = 4; r < 16; r += 4) {
            a0 += sxp[r]     * wreg[r];
            a1 += sxp[r + 1] * wreg[r + 1];
            a2 += sxp[r + 2] * wreg[r + 2];
            a3 += sxp[r + 3] * wreg[r + 3];
        }
        f32x4 av = (a0 + a1) + (a2 + a3);
        float acc = (av[0] + av[1]) + (av[2] + av[3]);
        acc += __shfl_xor(acc, 32);
        float d = rsqrtf((float)cursor[i] + 1.0f);
        acc = d * fmaxf(acc + bnf, 0.f);
        if (l < 32)
            ysb[(size_t)i * 32 + f] = __float2bfloat16(acc);
    }
}

// ---------------------------------------------------------------------------
// K3: persistent wave-per-node gather. M2 column l in 32 registers.
// Lane (q=l&7, s=l>>3): uint2 = 4 bf16/lane, 8 lanes/edge -> 8 edges in
// flight. Epilogue matvec via static-index unrolled shfl; Z/Ht; hr/hc.
__global__ __launch_bounds__(256) void k_gather(
        const int* __restrict__ cursor, const int* __restrict__ bin,
        const unsigned short* __restrict__ ysb,
        const float* __restrict__ M2, const float* __restrict__ cvec,
        const float* __restrict__ Wout,
        float* __restrict__ hr, float* __restrict__ hc, int N) {
    int tid = threadIdx.x;
    int w = tid >> 6, l = tid & 63;
    int q = l & 7, s = l >> 3;

    float mcol[32];
    #pragma unroll
    for (int k = 0; k < 32; ++k) mcol[k] = M2[k * 64 + l];
    float cvl = cvec[l];
    float w0l = Wout[l & 31];
    float w1l = Wout[32 + (l & 31)];

    int stride = gridDim.x * 4;
    for (int c = blockIdx.x * 4 + w; c < N; c += stride) {
        int truec = cursor[c];
        float dc = rsqrtf((float)truec + 1.0f);
        int cnt = truec < BINCAP ? truec : BINCAP;
        const int* bp = bin + ((size_t)c << 6);
        int myr = (l < cnt) ? bp[l] : 0;

        float a0 = 0.f, a1 = 0.f, a2 = 0.f, a3 = 0.f;
        uint2 sv = *(const uint2*)(ysb + (size_t)c * 32 + 4 * q);
        if (s == 0) {
            a0 = bflo(sv.x); a1 = bfhi(sv.x);
            a2 = bflo(sv.y); a3 = bfhi(sv.y);
        }
        for (int j = 0; j < cnt; j += 8) {
            int jj = j + s;
            if (jj < cnt) {
                int r = __shfl(myr, jj);
                uint2 v = *(const uint2*)(ysb + (size_t)r * 32 + 4 * q);
                a0 += bflo(v.x); a1 += bfhi(v.x);
                a2 += bflo(v.y); a3 += bfhi(v.y);
            }
        }
        a0 += __shfl_xor(a0, 8);  a1 += __shfl_xor(a1, 8);
        a2 += __shfl_xor(a2, 8);  a3 += __shfl_xor(a3, 8);
        a0 += __shfl_xor(a0, 16); a1 += __shfl_xor(a1, 16);
        a2 += __shfl_xor(a2, 16); a3 += __shfl_xor(a3, 16);
        a0 += __shfl_xor(a0, 32); a1 += __shfl_xor(a1, 32);
        a2 += __shfl_xor(a2, 32); a3 += __shfl_xor(a3, 32);
        // lane with q=kq now holds S[4kq..4kq+3] in a0..a3

        float acc = 0.f;
        #pragma unroll
        for (int kq = 0; kq < 8; ++kq) {
            float s0 = __shfl(a0, kq), s1 = __shfl(a1, kq);
            float s2 = __shfl(a2, kq), s3 = __shfl(a3, kq);
            acc += s0 * mcol[4 * kq]     + s1 * mcol[4 * kq + 1]
                 + s2 * mcol[4 * kq + 2] + s3 * mcol[4 * kq + 3];
        }
        float a = dc * acc + cvl;
        float v = (l < 32) ? (1.f / (1.f + __expf(-a))) : tanhf(a);
        float o = __shfl_xor(v, 32);
        float h = (1.f - v) * o;             // valid on lanes l<32
        float pr = h * w0l;
        float pc = h * w1l;
        #pragma unroll
        for (int m = 16; m >= 1; m >>= 1) {
            pr += __shfl_xor(pr, m);
            pc += __shfl_xor(pc, m);
        }
        if (l == 0) { hr[c] = pr; hc[c] = pc; }
    }
}

// ---------------------------------------------------------------------------
// K4: out[e] += hr[row[e]] + hc[col[e]]   (hr/hc 400KB each: L2/L3-resident)
__global__ __launch_bounds__(256) void k_edge_add(
        const int* __restrict__ row, const int* __restrict__ col,
        const float* __restrict__ hr, const float* __restrict__ hc,
        float* __restrict__ out, int E) {
    int e = blockIdx.x * 256 + threadIdx.x;
    if (e < E) out[e] += hr[row[e]] + hc[col[e]];
}

// ---------------------------------------------------------------------------
extern "C" void kernel_launch(void* const* d_in, const int* in_sizes, int n_in,
                              void* d_out, int out_size, void* d_ws, size_t ws_size,
                              hipStream_t stream) {
    const float* x    = (const float*)d_in[0];
    const int*   ei   = (const int*)  d_in[1];
    const float* ea   = (const float*)d_in[2];
    const float* Wn   = (const float*)d_in[3];
    const float* bn   = (const float*)d_in[4];
    const float* We   = (const float*)d_in[5];
    const float* be   = (const float*)d_in[6];
    const float* Wgz  = (const float*)d_in[7];
    const float* bgz  = (const float*)d_in[8];
    // d_in[9..10] = Wg_r, bg_r : dead (h0 == 0)
    const float* Wgh  = (const float*)d_in[11];
    const float* bgh  = (const float*)d_in[12];
    const float* Wlz  = (const float*)d_in[13];
    const float* blz  = (const float*)d_in[14];
    // d_in[15..16] = Wl_r, bl_r : dead
    const float* Wlh  = (const float*)d_in[17];
    const float* blh  = (const float*)d_in[18];
    const float* Wout = (const float*)d_in[19];
    const float* bout = (const float*)d_in[20];

    int N = in_sizes[0] / F_NODE;
    int E = in_sizes[1] / 2;
    const int* row = ei;
    const int* col = ei + E;

    // ws layout (float units):
    // ysb(bf16)[32N]=16N | bin(int)[64N] | Wnt[4096] | M2[2048] | Wet[1024]
    // | cvec[64] | hr[N] | hc[N] | cursor(int)[N]
    float* ws    = (float*)d_ws;
    __hip_bfloat16* ysb = (__hip_bfloat16*)ws;
    int*   bin   = (int*)(ws + (size_t)16 * N);
    float* Wnt   = ws + (size_t)80 * N;
    float* M2    = Wnt + 4096;
    float* Wet   = M2 + 2048;
    float* cvec  = Wet + 1024;
    float* hr    = cvec + 64;
    float* hc    = hr + N;
    int*   cursor= (int*)(hc + N);
    float* out   = (float*)d_out;

    hipMemsetAsync(cursor, 0, (size_t)N * sizeof(int), stream);

    k_prep<<<1, 256, 0, stream>>>(Wn, Wgz, Wgh, Wlz, Wlh, bgz, bgh, blz, blh, We,
                                  Wnt, M2, cvec, Wet);
    int EH = (E + 1) >> 1;          // MM edge half
    int NH = (N + 1) >> 1;          // col half
    int G  = (EH + 255) / 256;      // groups; fill coverage = 2*G*256 >= E
    // pass 1: fill cols [0,NH), MM edges [0,EH)
    k_fat<<<3 * G, 256, 0, stream>>>(row, col, cursor, bin, ea, Wet, be, Wout,
                                     bout, out, E, 0, NH, 0);
    // pass 2: fill cols [NH,N), MM edges [EH,E)
    k_fat<<<3 * G, 256, 0, stream>>>(row, col, cursor, bin, ea, Wet, be, Wout,
                                     bout, out, E, NH, N, EH);
    k_enc<<<768, 256, 0, stream>>>(x, bn, Wnt, cursor, ysb, N);
    k_gather<<<2048, 256, 0, stream>>>(cursor, bin, (const unsigned short*)ysb,
                                       M2, cvec, Wout, hr, hc, N);
    k_edge_add<<<(E + 255) / 256, 256, 0, stream>>>(row, col, hr, hc, out, E);
}

// Round 10
// 329.549 us; speedup vs baseline: 1.0701x; 1.0147x over previous
//
#include <hip/hip_runtime.h>
#include <hip/hip_bf16.h>

#define F_NODE 128
#define BINCAP 64

typedef float f32x4 __attribute__((ext_vector_type(4)));
typedef float f32x2 __attribute__((ext_vector_type(2)));

__device__ __forceinline__ float bflo(unsigned int v) {
    return __uint_as_float(v << 16);
}
__device__ __forceinline__ float bfhi(unsigned int v) {
    return __uint_as_float(v & 0xffff0000u);
}

// ---------------------------------------------------------------------------
// K0: zero cursor (all blocks) + fold weights (block 0).
//  Wnt[f][k] = W_node[k][f]                     (32 x 128 transposed)
//  M2[k][g]  = sum_j Wg_sel[k][j]*Wl_top[j][g&31]  (32 x 64; g<32 -> z)
//  cvec[g]   = sum_j bg[j]*Wl_top[j][g&31] + bl[g&31]
//  Wet[f][k] = W_edge[k][f]                     (32 x 32 transposed)
// (replaces hipMemsetAsync: rocclr fillBuffer ran at ~3.5 GB/s, 115us/replay)
__global__ void k_prep(const float* __restrict__ Wn,
                       const float* __restrict__ Wgz, const float* __restrict__ Wgh,
                       const float* __restrict__ Wlz, const float* __restrict__ Wlh,
                       const float* __restrict__ bgz, const float* __restrict__ bgh,
                       const float* __restrict__ blz, const float* __restrict__ blh,
                       const float* __restrict__ We,
                       float* __restrict__ Wnt, float* __restrict__ M2,
                       float* __restrict__ cvec, float* __restrict__ Wet,
                       int* __restrict__ cursor, int N) {
    int tid = threadIdx.x;
    // zero cursor, grid-wide (coalesced int writes)
    int t = blockIdx.x * 256 + tid;
    int gstride = gridDim.x * 256;
    for (; t < N; t += gstride) cursor[t] = 0;

    if (blockIdx.x != 0) return;
    for (int j = tid; j < 32 * 128; j += 256) {
        int f = j >> 7, k = j & 127;
        Wnt[j] = Wn[k * 32 + f];
    }
    for (int j = tid; j < 32 * 64; j += 256) {
        int k = j >> 6, g = j & 63, f = g & 31;
        const float* G = (g < 32) ? Wgz : Wgh;
        const float* L = (g < 32) ? Wlz : Wlh;   // top-half rows 0..31 of [64,32]
        float s = 0.f;
        for (int q = 0; q < 32; ++q) s += G[k * 32 + q] * L[q * 32 + f];
        M2[j] = s;
    }
    for (int j = tid; j < 64; j += 256) {
        int f = j & 31;
        const float* L  = (j < 32) ? Wlz : Wlh;
        const float* bg = (j < 32) ? bgz : bgh;
        const float* bl = (j < 32) ? blz : blh;
        float s = bl[f];
        for (int q = 0; q < 32; ++q) s += bg[q] * L[q * 32 + f];
        cvec[j] = s;
    }
    for (int j = tid; j < 32 * 32; j += 256) {
        int f = j >> 5, k = j & 31;
        Wet[j] = We[k * 32 + f];
    }
}

// ---------------------------------------------------------------------------
// FAT kernel, launched TWICE (sequential col-half passes).
//  slot = bid%3: 0,1 -> bin-fill scan chunks (keep only cols in [clo,chi):
//      instantaneous hot-line set = 3.2MB -> survives in L2, writes combine),
//  slot 2 -> edge matmul on this launch's edge half (NT ea loads).
// edge_index uses NORMAL loads: 12.8MB, L3-resident across passes.
__global__ __launch_bounds__(256) void k_fat(
        const int* __restrict__ row, const int* __restrict__ col,
        int* __restrict__ cursor, int* __restrict__ bin,
        const float* __restrict__ ea, const float* __restrict__ Wet,
        const float* __restrict__ be, const float* __restrict__ Wout,
        const float* __restrict__ bout, float* __restrict__ out,
        int E, int clo, int chi, int e0MM) {
    __shared__ float sW[1024];
    __shared__ float sb[32], sw3[32];
    int bid = blockIdx.x, tid = threadIdx.x;
    int slot = bid % 3;
    int sub  = bid / 3;

    if (slot < 2) {
        // ---- bin fill: scan chunk of the FULL edge list, filter col range ----
        int e = (sub * 2 + slot) * 256 + tid;
        if (e < E) {
            int c = col[e];
            if (c >= clo && c < chi) {
                int r = row[e];
                int p = atomicAdd(&cursor[c], 1);
                if (p < BINCAP) bin[((size_t)c << 6) + p] = r;
            }
        }
        return;
    }

    // ---- edge matmul: out[e] = relu(ea@We+be).w3 + b0 ----
    for (int j = tid; j < 1024; j += 256) sW[j] = Wet[j];
    if (tid < 32) { sb[tid] = be[tid]; sw3[tid] = Wout[64 + tid]; }
    __syncthreads();
    int e = e0MM + sub * 256 + tid;
    if (e >= E) return;
    f32x4 er[8];
    const f32x4* erow = (const f32x4*)(ea + (size_t)e * 32);
    #pragma unroll
    for (int r = 0; r < 8; ++r) er[r] = __builtin_nontemporal_load(erow + r);
    float p = 0.f;
    #pragma unroll 4
    for (int f = 0; f < 32; ++f) {
        const f32x4* wf = (const f32x4*)(sW + f * 32);
        f32x4 v0 = er[0] * wf[0];
        f32x4 v1 = er[1] * wf[1];
        #pragma unroll
        for (int k = 2; k < 8; k += 2) {
            v0 += er[k] * wf[k];
            v1 += er[k + 1] * wf[k + 1];
        }
        f32x4 v = v0 + v1;
        float sfin = (v[0] + v[1]) + (v[2] + v[3]);
        p += fmaxf(sb[f] + sfin, 0.f) * sw3[f];
    }
    __builtin_nontemporal_store(p + bout[0], out + e);
}

// ---------------------------------------------------------------------------
// K2: node encoder (runs AFTER fill -> degrees known). Wave-per-node:
// lane (f=l&31, kh=l>>5), weight column f K-half kh in 16 f32x4 registers;
// x staged wave-private in LDS; NT x loads.  Stores PRE-SCALED:
//   ysb[i][f] = bf16( rsqrt(deg_i+1) * relu(x_i @ Wn + bn)[f] )
__global__ __launch_bounds__(256) void k_enc(
        const float* __restrict__ x, const float* __restrict__ bn,
        const float* __restrict__ Wnt, const int* __restrict__ cursor,
        __hip_bfloat16* __restrict__ ysb, int N) {
    __shared__ float sx[4][128];
    int tid = threadIdx.x;
    int w = tid >> 6, l = tid & 63;
    int f = l & 31, kh = l >> 5;

    f32x4 wreg[16];
    const f32x4* wp = (const f32x4*)(Wnt + f * 128 + kh * 64);
    #pragma unroll
    for (int r = 0; r < 16; ++r) wreg[r] = wp[r];
    float bnf = bn[f];

    int stride = gridDim.x * 4;
    int i = blockIdx.x * 4 + w;
    f32x2 xv = {0.f, 0.f};
    if (i < N)
        xv = __builtin_nontemporal_load((const f32x2*)(x + (size_t)i * F_NODE) + l);

    for (; i < N; i += stride) {
        sx[w][2 * l]     = xv[0];
        sx[w][2 * l + 1] = xv[1];
        int inext = i + stride;
        if (inext < N)
            xv = __builtin_nontemporal_load(
                     (const f32x2*)(x + (size_t)inext * F_NODE) + l);

        const f32x4* sxp = (const f32x4*)(&sx[w][kh * 64]);
        f32x4 a0 = sxp[0] * wreg[0];
        f32x4 a1 = sxp[1] * wreg[1];
        f32x4 a2 = sxp[2] * wreg[2];
        f32x4 a3 = sxp[3] * wreg[3];
        #pragma unroll
        for (int r = 4; r < 16; r += 4) {
            a0 += sxp[r]     * wreg[r];
            a1 += sxp[r + 1] * wreg[r + 1];
            a2 += sxp[r + 2] * wreg[r + 2];
            a3 += sxp[r + 3] * wreg[r + 3];
        }
        f32x4 av = (a0 + a1) + (a2 + a3);
        float acc = (av[0] + av[1]) + (av[2] + av[3]);
        acc += __shfl_xor(acc, 32);
        float d = rsqrtf((float)cursor[i] + 1.0f);
        acc = d * fmaxf(acc + bnf, 0.f);
        if (l < 32)
            ysb[(size_t)i * 32 + f] = __float2bfloat16(acc);
    }
}

// ---------------------------------------------------------------------------
// K3: persistent wave-per-node gather. M2 column l in 32 registers.
// Lane (q=l&7, s=l>>3): uint2 = 4 bf16/lane, 8 lanes/edge -> 8 edges in
// flight. Epilogue matvec via static-index unrolled shfl; Z/Ht; hr/hc.
__global__ __launch_bounds__(256) void k_gather(
        const int* __restrict__ cursor, const int* __restrict__ bin,
        const unsigned short* __restrict__ ysb,
        const float* __restrict__ M2, const float* __restrict__ cvec,
        const float* __restrict__ Wout,
        float* __restrict__ hr, float* __restrict__ hc, int N) {
    int tid = threadIdx.x;
    int w = tid >> 6, l = tid & 63;
    int q = l & 7, s = l >> 3;

    float mcol[32];
    #pragma unroll
    for (int k = 0; k < 32; ++k) mcol[k] = M2[k * 64 + l];
    float cvl = cvec[l];
    float w0l = Wout[l & 31];
    float w1l = Wout[32 + (l & 31)];

    int stride = gridDim.x * 4;
    for (int c = blockIdx.x * 4 + w; c < N; c += stride) {
        int truec = cursor[c];
        float dc = rsqrtf((float)truec + 1.0f);
        int cnt = truec < BINCAP ? truec : BINCAP;
        const int* bp = bin + ((size_t)c << 6);
        int myr = (l < cnt) ? bp[l] : 0;

        float a0 = 0.f, a1 = 0.f, a2 = 0.f, a3 = 0.f;
        uint2 sv = *(const uint2*)(ysb + (size_t)c * 32 + 4 * q);
        if (s == 0) {
            a0 = bflo(sv.x); a1 = bfhi(sv.x);
            a2 = bflo(sv.y); a3 = bfhi(sv.y);
        }
        for (int j = 0; j < cnt; j += 8) {
            int jj = j + s;
            if (jj < cnt) {
                int r = __shfl(myr, jj);
                uint2 v = *(const uint2*)(ysb + (size_t)r * 32 + 4 * q);
                a0 += bflo(v.x); a1 += bfhi(v.x);
                a2 += bflo(v.y); a3 += bfhi(v.y);
            }
        }
        a0 += __shfl_xor(a0, 8);  a1 += __shfl_xor(a1, 8);
        a2 += __shfl_xor(a2, 8);  a3 += __shfl_xor(a3, 8);
        a0 += __shfl_xor(a0, 16); a1 += __shfl_xor(a1, 16);
        a2 += __shfl_xor(a2, 16); a3 += __shfl_xor(a3, 16);
        a0 += __shfl_xor(a0, 32); a1 += __shfl_xor(a1, 32);
        a2 += __shfl_xor(a2, 32); a3 += __shfl_xor(a3, 32);
        // lane with q=kq now holds S[4kq..4kq+3] in a0..a3

        float acc = 0.f;
        #pragma unroll
        for (int kq = 0; kq < 8; ++kq) {
            float s0 = __shfl(a0, kq), s1 = __shfl(a1, kq);
            float s2 = __shfl(a2, kq), s3 = __shfl(a3, kq);
            acc += s0 * mcol[4 * kq]     + s1 * mcol[4 * kq + 1]
                 + s2 * mcol[4 * kq + 2] + s3 * mcol[4 * kq + 3];
        }
        float a = dc * acc + cvl;
        float v = (l < 32) ? (1.f / (1.f + __expf(-a))) : tanhf(a);
        float o = __shfl_xor(v, 32);
        float h = (1.f - v) * o;             // valid on lanes l<32
        float pr = h * w0l;
        float pc = h * w1l;
        #pragma unroll
        for (int m = 16; m >= 1; m >>= 1) {
            pr += __shfl_xor(pr, m);
            pc += __shfl_xor(pc, m);
        }
        if (l == 0) { hr[c] = pr; hc[c] = pc; }
    }
}

// ---------------------------------------------------------------------------
// K4: out[e] += hr[row[e]] + hc[col[e]]   (hr/hc 400KB each: L2/L3-resident)
__global__ __launch_bounds__(256) void k_edge_add(
        const int* __restrict__ row, const int* __restrict__ col,
        const float* __restrict__ hr, const float* __restrict__ hc,
        float* __restrict__ out, int E) {
    int e = blockIdx.x * 256 + threadIdx.x;
    if (e < E) out[e] += hr[row[e]] + hc[col[e]];
}

// ---------------------------------------------------------------------------
extern "C" void kernel_launch(void* const* d_in, const int* in_sizes, int n_in,
                              void* d_out, int out_size, void* d_ws, size_t ws_size,
                              hipStream_t stream) {
    const float* x    = (const float*)d_in[0];
    const int*   ei   = (const int*)  d_in[1];
    const float* ea   = (const float*)d_in[2];
    const float* Wn   = (const float*)d_in[3];
    const float* bn   = (const float*)d_in[4];
    const float* We   = (const float*)d_in[5];
    const float* be   = (const float*)d_in[6];
    const float* Wgz  = (const float*)d_in[7];
    const float* bgz  = (const float*)d_in[8];
    // d_in[9..10] = Wg_r, bg_r : dead (h0 == 0)
    const float* Wgh  = (const float*)d_in[11];
    const float* bgh  = (const float*)d_in[12];
    const float* Wlz  = (const float*)d_in[13];
    const float* blz  = (const float*)d_in[14];
    // d_in[15..16] = Wl_r, bl_r : dead
    const float* Wlh  = (const float*)d_in[17];
    const float* blh  = (const float*)d_in[18];
    const float* Wout = (const float*)d_in[19];
    const float* bout = (const float*)d_in[20];

    int N = in_sizes[0] / F_NODE;
    int E = in_sizes[1] / 2;
    const int* row = ei;
    const int* col = ei + E;

    // ws layout (float units):
    // ysb(bf16)[32N]=16N | bin(int)[64N] | Wnt[4096] | M2[2048] | Wet[1024]
    // | cvec[64] | hr[N] | hc[N] | cursor(int)[N]
    float* ws    = (float*)d_ws;
    __hip_bfloat16* ysb = (__hip_bfloat16*)ws;
    int*   bin   = (int*)(ws + (size_t)16 * N);
    float* Wnt   = ws + (size_t)80 * N;
    float* M2    = Wnt + 4096;
    float* Wet   = M2 + 2048;
    float* cvec  = Wet + 1024;
    float* hr    = cvec + 64;
    float* hc    = hr + N;
    int*   cursor= (int*)(hc + N);
    float* out   = (float*)d_out;

    // zero cursor + fold weights in one kernel (no hipMemsetAsync: the
    // rocclr fillBuffer kernel cost ~115us/replay at this size)
    k_prep<<<400, 256, 0, stream>>>(Wn, Wgz, Wgh, Wlz, Wlh, bgz, bgh, blz, blh,
                                    We, Wnt, M2, cvec, Wet, cursor, N);
    int EH = (E + 1) >> 1;          // MM edge half
    int NH = (N + 1) >> 1;          // col half
    int G  = (EH + 255) / 256;      // groups; fill coverage = 2*G*256 >= E
    // pass 1: fill cols [0,NH), MM edges [0,EH)
    k_fat<<<3 * G, 256, 0, stream>>>(row, col, cursor, bin, ea, Wet, be, Wout,
                                     bout, out, E, 0, NH, 0);
    // pass 2: fill cols [NH,N), MM edges [EH,E)
    k_fat<<<3 * G, 256, 0, stream>>>(row, col, cursor, bin, ea, Wet, be, Wout,
                                     bout, out, E, NH, N, EH);
    k_enc<<<768, 256, 0, stream>>>(x, bn, Wnt, cursor, ysb, N);
    k_gather<<<2048, 256, 0, stream>>>(cursor, bin, (const unsigned short*)ysb,
                                       M2, cvec, Wout, hr, hc, N);
    k_edge_add<<<(E + 255) / 256, 256, 0, stream>>>(row, col, hr, hc, out, E);
}